// Round 14
// baseline (171.299 us; speedup 1.0000x reference)
//
#include <hip/hip_runtime.h>
#include <hip/hip_bf16.h>
#include <stdint.h>

#define DEV __device__ __forceinline__

typedef unsigned short u16;
typedef unsigned char u8;
typedef __attribute__((ext_vector_type(8))) short bf16x8;        // 8 bf16 MFMA A/B frag
typedef __attribute__((ext_vector_type(4))) float f32x4;         // MFMA C/D frag
typedef __attribute__((ext_vector_type(4))) int i32x4;           // i8 MFMA frag / acc

DEV u16 bf(float v) {
  __hip_bfloat16 h = __float2bfloat16(v);
  union { __hip_bfloat16 h; u16 u; } x; x.h = h;
  return x.u;
}

// sigmoid(v/sqrt(512)) = 1/(1+exp2(v * -log2(e)/sqrt(512)))
DEV float sigmoid_s(float v) {
  float e = __builtin_amdgcn_exp2f(v * -0.0637587143f);
  return __builtin_amdgcn_rcpf(1.0f + e);
}

DEV signed char qi8(float v) {
  float t = fminf(fmaxf(v * 31.75f, -127.f), 127.f);   // scale 127/4
  return (signed char)(int)rintf(t);
}

DEV void gld_lds(const void* g, void* l) {
  __builtin_amdgcn_global_load_lds(
      (const __attribute__((address_space(1))) uint32_t*)g,
      (__attribute__((address_space(3))) uint32_t*)l, 16, 0, 0);
}

// ---------------- f32 -> bf16 conversion (x, Wq, Wv) ----------------
__global__ void conv_kernel(const float* __restrict__ x,
                            const float* __restrict__ Wq,
                            const float* __restrict__ Wv,
                            u16* __restrict__ xb,
                            u16* __restrict__ wqb,
                            u16* __restrict__ wvb) {
  const int NX4 = (16384 * 512) / 4;
  const int NW4 = (512 * 512) / 4;
  int i = blockIdx.x * blockDim.x + threadIdx.x;
  const float4* src; u16* dst; int off;
  if (i < NX4)            { src = (const float4*)x;  dst = xb;  off = i; }
  else if (i < NX4 + NW4) { src = (const float4*)Wq; dst = wqb; off = i - NX4; }
  else                    { src = (const float4*)Wv; dst = wvb; off = i - NX4 - NW4; }
  float4 f = src[off];
  ushort4 o = make_ushort4(bf(f.x), bf(f.y), bf(f.z), bf(f.w));
  ((ushort4*)dst)[off] = o;
}

// ---------------- fused projection GEMM: [q | v] in one pass ---------------
__global__ __launch_bounds__(256, 2)
void gemm_proj(const u16* __restrict__ xb,
               const u16* __restrict__ wqb,
               const u16* __restrict__ wvb,
               const float* __restrict__ bq,
               const float* __restrict__ bv,
               signed char* __restrict__ qb8,
               signed char* __restrict__ vT8) {
  constexpr int BK = 64, NBN = 8, NBM = 128;
  constexpr int TILE = 256 * 64;            // u16 per buffer
  __shared__ u16 lds[2 * TILE];             // 64 KB

  const int tid  = threadIdx.x;
  const int lane = tid & 63;
  const int w    = tid >> 6;
  const int wr   = w >> 1, wc = w & 1;

  const int nwg = (int)gridDim.x;           // 1024
  const int id  = blockIdx.x;
  const int swz = (id & 7) * (nwg >> 3) + (id >> 3);
  const int bn  = swz % NBN;
  const int bm  = (swz / NBN) % NBM;

  const u16* A = xb + (long)bm * 128 * 512;
  const u16* B = (bn < 4) ? wqb + (long)bn * 128 * 512
                          : wvb + (long)(bn - 4) * 128 * 512;

  const int lrow = lane & 15;
  const int rx   = lane & 7;
  const int srow = lane >> 3;
  const int scol = ((lane & 7) ^ srow) << 3;

  const u16* srcs[8];
#pragma unroll
  for (int c = 0; c < 8; ++c) {
    int row = (w * 8 + c) * 8 + srow;       // 0..255 (A | B)
    srcs[c] = (row < 128) ? A + (long)row * 512 + scol
                          : B + (long)(row - 128) * 512 + scol;
  }

  f32x4 acc[4][4] = {};

#pragma unroll
  for (int c = 0; c < 8; ++c)
    gld_lds(srcs[c], &lds[(w * 8 + c) * 512]);

  int p = 0;
  for (int kt = 0; kt < 8; ++kt) {
    if (kt + 1 < 8) {
#pragma unroll
      for (int c = 0; c < 8; ++c)
        gld_lds(srcs[c] + (kt + 1) * BK, &lds[(p ^ 1) * TILE + (w * 8 + c) * 512]);
      asm volatile("s_waitcnt vmcnt(8)" ::: "memory");
    } else {
      asm volatile("s_waitcnt vmcnt(0)" ::: "memory");
    }
    __builtin_amdgcn_s_barrier();
    asm volatile("" ::: "memory");

    const u16* Alds = &lds[p * TILE];
    const u16* Blds = &lds[p * TILE + 128 * 64];
#pragma unroll
    for (int ks = 0; ks < 2; ++ks) {
      const int sl = ((ks * 4 + (lane >> 4)) ^ rx) << 3;
      bf16x8 af[4], bfr[4];
#pragma unroll
      for (int t = 0; t < 4; ++t) {
        af[t]  = *(const bf16x8*)&Alds[(wr * 64 + t * 16 + lrow) * BK + sl];
        bfr[t] = *(const bf16x8*)&Blds[(wc * 64 + t * 16 + lrow) * BK + sl];
      }
#pragma unroll
      for (int mt = 0; mt < 4; ++mt)
#pragma unroll
        for (int nt = 0; nt < 4; ++nt)
          acc[mt][nt] = __builtin_amdgcn_mfma_f32_16x16x32_bf16(af[mt], bfr[nt], acc[mt][nt], 0, 0, 0);
    }

    asm volatile("" ::: "memory");
    __builtin_amdgcn_s_barrier();
    p ^= 1;
  }

  const int row0 = bm * 128 + wr * 64;
  const int rsub = (lane >> 4) << 2;

  if (bn < 4) {   // q half: row-major i8, bias per col
#pragma unroll
    for (int mt = 0; mt < 4; ++mt)
#pragma unroll
      for (int nt = 0; nt < 4; ++nt) {
        int col = bn * 128 + wc * 64 + nt * 16 + lrow;
        float b = bq[col];
#pragma unroll
        for (int r = 0; r < 4; ++r)
          qb8[(long)(row0 + mt * 16 + rsub + r) * 512 + col] = qi8(acc[mt][nt][r] + b);
      }
  } else {        // v half: transposed packed store into vT8[e][m]
#pragma unroll
    for (int mt = 0; mt < 4; ++mt)
#pragma unroll
      for (int nt = 0; nt < 4; ++nt) {
        int e = (bn - 4) * 128 + wc * 64 + nt * 16 + lrow;
        float b = bv[e];
        int rowb = row0 + mt * 16 + rsub;
        uint32_t pk = ((uint32_t)(u8)qi8(acc[mt][nt][0] + b)) |
                      ((uint32_t)(u8)qi8(acc[mt][nt][1] + b) << 8) |
                      ((uint32_t)(u8)qi8(acc[mt][nt][2] + b) << 16) |
                      ((uint32_t)(u8)qi8(acc[mt][nt][3] + b) << 24);
        *(uint32_t*)&vT8[(long)e * 16384 + rowb] = pk;
      }
  }
}

// ---------------- fused sigmoid-attention, all-i8 --------------------------
// Per block: 64 q-rows x 512 d, one batch z. 16 waves. kv-tiles of 128.
// Q_lds [64][512B] @0 (staged once); K_lds [128][512B] @32768 (restaged per
// tile, counted vmcnt overlaps sigmoid+PV); P_lds [64 q][144B] @98304.
// QK: S^T = mfma(K, Q) per wave: [16 kv (kvg)][32 q (qh)]; sigmoid -> u8
// -> P_lds; PV: O += mfma(P, V) with V gathered to regs (early-issued).
__global__ __launch_bounds__(1024, 4)
void fused_attn_i8(const signed char* __restrict__ Qm,   // qb8 [16384][512]
                   const signed char* __restrict__ Vt,   // vT8 [512][16384]
                   float* __restrict__ Ot) {             // out [16384][512]
  __shared__ signed char lds[107520];

  const int tid  = threadIdx.x;
  const int lane = tid & 63;
  const int w    = tid >> 6;          // 0..15
  const int hi   = lane >> 4;         // 0..3
  const int lrow = lane & 15;
  const int kvg  = w >> 1;            // 0..7  (kv 16-row group for QK)
  const int qh   = w & 1;             // q half for QK

  const int id  = blockIdx.x;         // grid 256
  const int swz = (id & 7) * 32 + (id >> 3);
  const int z   = swz >> 6;
  const int qb  = swz & 63;
  const long R0 = (long)z * 4096 + (long)qb * 64;   // global q-row base

  const int key = lrow & 7;           // read-slot XOR key (rows: &7 == lrow&7)

  // ---- stage Q once (2 rounds; wave covers q rows 2*(16r+w),+1)
#pragma unroll
  for (int r = 0; r < 2; ++r) {
    int q = 2 * (r * 16 + w) + (lane >> 5);
    int s = lane & 31, c = s >> 3, s3 = s & 7;
    gld_lds(Qm + (R0 + q) * 512 + c * 128 + ((s3 ^ (q & 7)) << 4),
            &lds[(r * 16 + w) * 1024]);
  }

  // K staging sources (4 rounds/tile); advance by kt*65536
  const signed char* ksrc[4];
  {
    int s = lane & 31, c = s >> 3, s3 = s & 7;
#pragma unroll
    for (int r = 0; r < 4; ++r) {
      int kv = 2 * (r * 16 + w) + (lane >> 5);
      ksrc[r] = Qm + ((long)z * 4096 + kv) * 512 + c * 128 + ((s3 ^ (kv & 7)) << 4);
    }
  }
  // V gather sources (regs, no LDS); advance by kt*128
  const signed char* vsrc[2][2];
#pragma unroll
  for (int nt2 = 0; nt2 < 2; ++nt2)
#pragma unroll
    for (int ks2 = 0; ks2 < 2; ++ks2)
      vsrc[nt2][ks2] = Vt + (long)(w * 32 + nt2 * 16 + lrow) * 16384
                          + (long)z * 4096 + ks2 * 64 + hi * 16;

  // prologue: K(0) + V(0)
#pragma unroll
  for (int r = 0; r < 4; ++r)
    gld_lds(ksrc[r], &lds[32768 + (r * 16 + w) * 1024]);
  i32x4 vc00 = *(const i32x4*)vsrc[0][0];
  i32x4 vc01 = *(const i32x4*)vsrc[0][1];
  i32x4 vc10 = *(const i32x4*)vsrc[1][0];
  i32x4 vc11 = *(const i32x4*)vsrc[1][1];
  asm volatile("s_waitcnt vmcnt(0)" ::: "memory");
  __builtin_amdgcn_s_barrier();
  asm volatile("" ::: "memory");

  i32x4 o[4][2] = {};
  const int kvrow = kvg * 16 + lrow;

  for (int kt = 0; kt < 32; ++kt) {
    // ---- QK: S^T[16 kv][32 q] per wave (16 MFMA)
    i32x4 S0 = {0, 0, 0, 0}, S1 = {0, 0, 0, 0};
#pragma unroll
    for (int kk = 0; kk < 8; ++kk) {
      const int off = (kk >> 1) * 128 + ((((kk & 1) * 4 + hi) ^ key) << 4);
      i32x4 a  = *(const i32x4*)&lds[32768 + kvrow * 512 + off];
      i32x4 b0 = *(const i32x4*)&lds[(qh * 32 + lrow) * 512 + off];
      i32x4 b1 = *(const i32x4*)&lds[(qh * 32 + 16 + lrow) * 512 + off];
      S0 = __builtin_amdgcn_mfma_i32_16x16x64_i8(a, b0, S0, 0, 0, 0);
      S1 = __builtin_amdgcn_mfma_i32_16x16x64_i8(a, b1, S1, 0, 0, 0);
    }
    asm volatile("s_waitcnt lgkmcnt(0)" ::: "memory");   // K reads landed
    __builtin_amdgcn_s_barrier();
    asm volatile("" ::: "memory");

    // restage K(kt+1) + gather V(kt+1) (in flight across barriers)
    i32x4 vn00, vn01, vn10, vn11;
    if (kt + 1 < 32) {
#pragma unroll
      for (int r = 0; r < 4; ++r)
        gld_lds(ksrc[r] + (long)(kt + 1) * 65536, &lds[32768 + (r * 16 + w) * 1024]);
      vn00 = *(const i32x4*)(vsrc[0][0] + (kt + 1) * 128);
      vn01 = *(const i32x4*)(vsrc[0][1] + (kt + 1) * 128);
      vn10 = *(const i32x4*)(vsrc[1][0] + (kt + 1) * 128);
      vn11 = *(const i32x4*)(vsrc[1][1] + (kt + 1) * 128);
    }

    // ---- sigmoid -> u8 -> P_lds [64 q][144 B]
#pragma unroll
    for (int nt = 0; nt < 2; ++nt) {
      i32x4 S = nt ? S1 : S0;
      uint32_t pk = 0;
#pragma unroll
      for (int r = 0; r < 4; ++r) {
        float v = (float)S[r] * 9.91941e-4f;      // (4/127)^2 dequant
        pk |= (uint32_t)(u8)(int)(sigmoid_s(v) * 127.f + 0.5f) << (8 * r);
      }
      int q = qh * 32 + nt * 16 + lrow;
      *(uint32_t*)&lds[98304 + q * 144 + kvg * 16 + hi * 4] = pk;
    }
    asm volatile("s_waitcnt lgkmcnt(0)" ::: "memory");   // P writes landed
    __builtin_amdgcn_s_barrier();
    asm volatile("" ::: "memory");

    // ---- PV: O[64 q][32 d] per wave (16 MFMA)
#pragma unroll
    for (int ks2 = 0; ks2 < 2; ++ks2) {
      i32x4 pa[4];
#pragma unroll
      for (int qg = 0; qg < 4; ++qg)
        pa[qg] = *(const i32x4*)&lds[98304 + (qg * 16 + lrow) * 144 + ks2 * 64 + hi * 16];
      i32x4 v0 = ks2 ? vc01 : vc00;
      i32x4 v1 = ks2 ? vc11 : vc10;
#pragma unroll
      for (int qg = 0; qg < 4; ++qg) {
        o[qg][0] = __builtin_amdgcn_mfma_i32_16x16x64_i8(pa[qg], v0, o[qg][0], 0, 0, 0);
        o[qg][1] = __builtin_amdgcn_mfma_i32_16x16x64_i8(pa[qg], v1, o[qg][1], 0, 0, 0);
      }
    }
    asm volatile("s_waitcnt vmcnt(0)" ::: "memory");     // K(kt+1)+V(kt+1) landed
    if (kt + 1 < 32) { vc00 = vn00; vc01 = vn01; vc10 = vn10; vc11 = vn11; }
    asm volatile("s_waitcnt lgkmcnt(0)" ::: "memory");   // P reads landed (WAR)
    __builtin_amdgcn_s_barrier();
    asm volatile("" ::: "memory");
  }

  // ---- epilogue: O scale (1/127)*(4/127), f32 store
  const float SC = 4.0f / 16129.0f;
#pragma unroll
  for (int qg = 0; qg < 4; ++qg)
#pragma unroll
    for (int nt2 = 0; nt2 < 2; ++nt2)
#pragma unroll
      for (int r = 0; r < 4; ++r) {
        long row = R0 + qg * 16 + hi * 4 + r;
        int col = w * 32 + nt2 * 16 + lrow;
        Ot[row * 512 + col] = SC * (float)o[qg][nt2][r];
      }
}

// ---------------- launch ----------------
extern "C" void kernel_launch(void* const* d_in, const int* in_sizes, int n_in,
                              void* d_out, int out_size, void* d_ws, size_t ws_size,
                              hipStream_t stream) {
  const float* x  = (const float*)d_in[0];   // [4,4096,512]
  const float* Wq = (const float*)d_in[1];   // [512,512]
  const float* bq = (const float*)d_in[2];   // [512]
  const float* Wv = (const float*)d_in[3];   // [512,512]
  const float* bv = (const float*)d_in[4];   // [512]
  float* out = (float*)d_out;                // [4,4096,512] f32

  // workspace carve (~50 MB; P buffer no longer needed)
  char* wsb = (char*)d_ws;
  u16* xb  = (u16*)wsb;                                   // [16384][512] bf16  32 MB
  signed char* qb8 = (signed char*)(wsb + 33554432);      // [16384][512] i8     8 MB
  signed char* vT8 = (signed char*)(wsb + 41943040);      // [512][16384] i8     8 MB
  u16* wqb = (u16*)(wsb + 50331648);                      // [512][512] bf16
  u16* wvb = (u16*)(wsb + 50855936);                      // [512][512] bf16

  conv_kernel<<<8704, 256, 0, stream>>>(x, Wq, Wv, xb, wqb, wvb);

  // fused: q8 = qi8(xb Wq^T + bq), vT8 = qi8(xb Wv^T + bv)^T
  gemm_proj<<<1024, 256, 0, stream>>>(xb, wqb, wvb, bq, bv, qb8, vT8);

  // O = sigmoid-attention(q8, q8, v8), fully fused (no P materialization)
  fused_attn_i8<<<256, 1024, 0, stream>>>(qb8, vT8, out);
}